// Round 5
// baseline (820.520 us; speedup 1.0000x reference)
//
#include <hip/hip_runtime.h>

// ---------------------------------------------------------------------------
// Autoencoder: x+embed -> Linear(2048,1536)+GELU -> Linear(1536,256) -> top4
//              -> softmax -> mix components(256,3) -> Linear(3,1536)+GELU
//              -> Linear(1536,2048).
// Round-5: enc1 + dec2 moved to a phased double-buffered pipeline
// (T3+T4 counted-vmcnt schedule, T5 setprio, T2 packed-swizzle layout) --
// the m97-style 2-barrier loop measured at its known ~900 TF ceiling
// (893 TF, MfmaUtil 39.5%, conflicts 0 after round-4 swizzle).
// Encoder split-bf16 (3-MFMA, fp32-class logits) + fp64 rescue of
// borderline top-k rows (gap < TAU). enc2 stays on the 128^2 kernel.
// ---------------------------------------------------------------------------

typedef float  f32x4  __attribute__((ext_vector_type(4)));
typedef short  short8 __attribute__((ext_vector_type(8)));

#define DEVINL __device__ __forceinline__

constexpr int  NB      = 16384;
constexpr int  IN_DIM  = 2048;
constexpr int  HID     = 1536;
constexpr int  NC      = 256;
constexpr long ENC_ELEMS = (long)NB * NC * 3;
constexpr float TAU = 2e-5f;
constexpr int  MAXR = 64;
constexpr int  NKT1 = IN_DIM / 32;   // 64  (enc1 K-subtiles)
constexpr int  NKT2 = HID / 32;      // 48  (enc2 / dec2 K-subtiles)

DEVINL unsigned short f2bf(float f) {    // fp32 -> bf16 bits, RNE
  unsigned int u = __builtin_bit_cast(unsigned int, f);
  u = u + 0x7fffu + ((u >> 16) & 1u);
  return (unsigned short)(u >> 16);
}
DEVINL float bf2f(unsigned short h) {
  unsigned int u = ((unsigned int)h) << 16;
  return __builtin_bit_cast(float, u);
}
DEVINL float gelu_f(float v) {
  return 0.5f * v * (1.0f + erff(v * 0.70710678118654752440f));
}
DEVINL void llds16(const void* g, void* l) {   // async global->LDS, 16B/lane
  __builtin_amdgcn_global_load_lds(
      (const __attribute__((address_space(1))) void*)g,
      (__attribute__((address_space(3))) void*)l, 16, 0, 0);
}
DEVINL f32x4 mfma_bf16(short8 a, short8 b, f32x4 c) {
  return __builtin_amdgcn_mfma_f32_16x16x32_bf16(a, b, c, 0, 0, 0);
}
// packed-layout element offset for element (row-in-128-tile, k-in-32-chunk)
DEVINL long packed_off(long tileIdx, int rowp, int kq, int e) {
  int slot = kq ^ ((rowp >> 1) & 3);
  return (tileIdx * 512 + rowp * 4 + slot) * 8 + e;
}
DEVINL int swz_idx(int rowp, int kq) {          // element index inside an LDS subtile
  return (rowp * 4 + (kq ^ ((rowp >> 1) & 3))) * 8;
}

// ---------------------------------------------------------------------------
// Transpose (K,N) fp32 -> packed-swizzled (N,K) bf16 hi (+ optional lo).
// ---------------------------------------------------------------------------
__global__ __launch_bounds__(256) void transpose_split_kernel(
    const float* __restrict__ in, int K, int N, int nkt,
    unsigned short* __restrict__ outH, unsigned short* __restrict__ outL)
{
  __shared__ float t[32][33];
  int tx = threadIdx.x & 31, ty = threadIdx.x >> 5;   // 32 x 8
  int n0 = blockIdx.x * 32, k0 = blockIdx.y * 32;
#pragma unroll
  for (int i = 0; i < 4; ++i)
    t[ty + i * 8][tx] = in[(long)(k0 + ty + i * 8) * N + n0 + tx];
  __syncthreads();

  int n = n0 + tx;
  int ntile = n >> 7, rowp = n & 127;
  int Kt = k0 >> 5;
  int j = ty & 3;                       // kq of this block
  long off = packed_off((long)ntile * nkt + Kt, rowp, j, 0);
  if (ty < 4) {
    short8 hv;
#pragma unroll
    for (int e = 0; e < 8; ++e) hv[e] = (short)f2bf(t[j * 8 + e][tx]);
    *(short8*)(outH + off) = hv;
  } else if (outL) {
    short8 lv;
#pragma unroll
    for (int e = 0; e < 8; ++e) {
      float f = t[j * 8 + e][tx];
      lv[e] = (short)f2bf(f - bf2f(f2bf(f)));
    }
    *(short8*)(outL + off) = lv;
  }
}

// ---------------------------------------------------------------------------
// Pre-split pass: Xh/Xl = split(x + embed[li]) in packed-swizzled layout.
// ---------------------------------------------------------------------------
__global__ __launch_bounds__(256) void split_x_kernel(
    const float* __restrict__ x, const float* __restrict__ embedMat,
    const int* __restrict__ liPtr,
    unsigned short* __restrict__ Xh, unsigned short* __restrict__ Xl)
{
  long g = (long)blockIdx.x * 256 + threadIdx.x;      // 16B-block index
  int  li = liPtr[0];
  int  Mtile = (int)(g >> 15);
  int  rem = (int)(g & 32767);
  int  Kt = rem >> 9;
  int  b  = rem & 511;
  int  rowp = b >> 2, slot = b & 3;
  int  kq = slot ^ ((rowp >> 1) & 3);
  long grow = (long)Mtile * 128 + rowp;
  int  k = Kt * 32 + kq * 8;
  const float* xr = x + grow * IN_DIM + k;
  const float* er = embedMat + (long)li * IN_DIM + k;
  f32x4 a0 = *(const f32x4*)(xr);
  f32x4 a1 = *(const f32x4*)(xr + 4);
  f32x4 e0 = *(const f32x4*)(er);
  f32x4 e1 = *(const f32x4*)(er + 4);
  short8 hv, lv;
#pragma unroll
  for (int j2 = 0; j2 < 4; ++j2) {
    float f = a0[j2] + e0[j2];
    unsigned short hb = f2bf(f);
    hv[j2] = (short)hb; lv[j2] = (short)f2bf(f - bf2f(hb));
  }
#pragma unroll
  for (int j2 = 0; j2 < 4; ++j2) {
    float f = a1[j2] + e1[j2];
    unsigned short hb = f2bf(f);
    hv[4 + j2] = (short)hb; lv[4 + j2] = (short)f2bf(f - bf2f(hb));
  }
  *(short8*)(Xh + g * 8) = hv;
  *(short8*)(Xl + g * 8) = lv;
}

// ---------------------------------------------------------------------------
// PIPELINED SPLIT GEMM (enc1): 128x256 tile, BK=32, 8 waves, 4 phases/K-step.
// Double-buffered LDS; tile t+1 staged during tile t's phases; one vmcnt(0)
// per K-step (only next-tile loads outstanding => counted semantics).
// OUT: GELU + packed-swizzled bf16 hi/lo (Ch/Cl) for the next GEMM's A.
// ---------------------------------------------------------------------------
__global__ __launch_bounds__(512, 1) void gemm_pipe_split_kernel(
    const unsigned short* __restrict__ Ah, const unsigned short* __restrict__ Al,
    const unsigned short* __restrict__ Bh, const unsigned short* __restrict__ Bl,
    int nkt, const float* __restrict__ bias,
    unsigned short* __restrict__ Ch, unsigned short* __restrict__ Cl,
    int nktOut, int nbn)
{
  __shared__ alignas(16) unsigned short sAh[2][4096];
  __shared__ alignas(16) unsigned short sAl[2][4096];
  __shared__ alignas(16) unsigned short sBh[2][8192];
  __shared__ alignas(16) unsigned short sBl[2][8192];
  __shared__ float sBias[256];

  int tid = threadIdx.x;
  int nwg = gridDim.x, q = nwg >> 3, b0 = blockIdx.x;   // XCD swizzle (nwg%8==0)
  int sw = (b0 & 7) * q + (b0 >> 3);
  int bm = sw / nbn, bn = sw % nbn;

  if (tid < 256) sBias[tid] = bias[bn * 256 + tid];

  int wid = tid >> 6, lane = tid & 63;
  int wm = wid >> 2, wn = wid & 3;                      // 2M x 4N waves
  int l15 = lane & 15, kq = lane >> 4;

  int aidx[4], bidx[4];
#pragma unroll
  for (int m = 0; m < 4; ++m) aidx[m] = swz_idx(wm * 64 + m * 16 + l15, kq);
#pragma unroll
  for (int n = 0; n < 4; ++n) {
    int r = wn * 64 + n * 16 + l15;
    bidx[n] = (r >> 7) * 4096 + swz_idx(r & 127, kq);
  }

  f32x4 acc[4][4] = {};

  // prologue: stage K-step 0 into buffer 0
  {
    long at = (long)(bm * nkt);
    llds16((const char*)Ah + at * 8192 + tid * 16, (char*)sAh[0] + tid * 16);
    llds16((const char*)Al + at * 8192 + tid * 16, (char*)sAl[0] + tid * 16);
    long bt0 = (long)((bn * 2) * nkt), bt1 = (long)((bn * 2 + 1) * nkt);
    llds16((const char*)Bh + bt0 * 8192 + tid * 16, (char*)sBh[0] + tid * 16);
    llds16((const char*)Bh + bt1 * 8192 + tid * 16, (char*)sBh[0] + 8192 + tid * 16);
    llds16((const char*)Bl + bt0 * 8192 + tid * 16, (char*)sBl[0] + tid * 16);
    llds16((const char*)Bl + bt1 * 8192 + tid * 16, (char*)sBl[0] + 8192 + tid * 16);
  }
  asm volatile("s_waitcnt vmcnt(0)");
  __builtin_amdgcn_sched_barrier(0);
  __builtin_amdgcn_s_barrier();

  for (int t = 0; t < nkt; ++t) {
    int cur = t & 1, nxt = cur ^ 1;
    bool pre = (t + 1 < nkt);
    short8 ah[4], al[4], bh, bl;

    // ---- phase 0: A frags + B[0]; stage Ah/Al(t+1)
#pragma unroll
    for (int m = 0; m < 4; ++m) {
      ah[m] = *(const short8*)&sAh[cur][aidx[m]];
      al[m] = *(const short8*)&sAl[cur][aidx[m]];
    }
    bh = *(const short8*)&sBh[cur][bidx[0]];
    bl = *(const short8*)&sBl[cur][bidx[0]];
    if (pre) {
      long at = (long)(bm * nkt + t + 1);
      llds16((const char*)Ah + at * 8192 + tid * 16, (char*)sAh[nxt] + tid * 16);
      llds16((const char*)Al + at * 8192 + tid * 16, (char*)sAl[nxt] + tid * 16);
    }
    __builtin_amdgcn_s_barrier();
    asm volatile("s_waitcnt lgkmcnt(0)");
    __builtin_amdgcn_sched_barrier(0);
    __builtin_amdgcn_s_setprio(1);
#pragma unroll
    for (int m = 0; m < 4; ++m) {
      acc[m][0] = mfma_bf16(ah[m], bh, acc[m][0]);
      acc[m][0] = mfma_bf16(al[m], bh, acc[m][0]);
      acc[m][0] = mfma_bf16(ah[m], bl, acc[m][0]);
    }
    __builtin_amdgcn_s_setprio(0);
    __builtin_amdgcn_sched_barrier(0);
    __builtin_amdgcn_s_barrier();

    // ---- phases 1..3: B[ph]; stage Bh(ph==1) / Bl(ph==2)
#pragma unroll
    for (int ph = 1; ph < 4; ++ph) {
      bh = *(const short8*)&sBh[cur][bidx[ph]];
      bl = *(const short8*)&sBl[cur][bidx[ph]];
      if (pre && ph == 1) {
        long bt0 = (long)((bn * 2) * nkt + t + 1), bt1 = (long)((bn * 2 + 1) * nkt + t + 1);
        llds16((const char*)Bh + bt0 * 8192 + tid * 16, (char*)sBh[nxt] + tid * 16);
        llds16((const char*)Bh + bt1 * 8192 + tid * 16, (char*)sBh[nxt] + 8192 + tid * 16);
      }
      if (pre && ph == 2) {
        long bt0 = (long)((bn * 2) * nkt + t + 1), bt1 = (long)((bn * 2 + 1) * nkt + t + 1);
        llds16((const char*)Bl + bt0 * 8192 + tid * 16, (char*)sBl[nxt] + tid * 16);
        llds16((const char*)Bl + bt1 * 8192 + tid * 16, (char*)sBl[nxt] + 8192 + tid * 16);
      }
      __builtin_amdgcn_s_barrier();
      asm volatile("s_waitcnt lgkmcnt(0)");
      __builtin_amdgcn_sched_barrier(0);
      __builtin_amdgcn_s_setprio(1);
#pragma unroll
      for (int m = 0; m < 4; ++m) {
        acc[m][ph] = mfma_bf16(ah[m], bh, acc[m][ph]);
        acc[m][ph] = mfma_bf16(al[m], bh, acc[m][ph]);
        acc[m][ph] = mfma_bf16(ah[m], bl, acc[m][ph]);
      }
      __builtin_amdgcn_s_setprio(0);
      __builtin_amdgcn_sched_barrier(0);
      __builtin_amdgcn_s_barrier();
    }

    // ---- end of K-step: drain next-tile staging, flip buffers
    asm volatile("s_waitcnt vmcnt(0)");
    __builtin_amdgcn_sched_barrier(0);
    __builtin_amdgcn_s_barrier();
  }

  // epilogue: C/D layout col = lane&15, row = (lane>>4)*4 + r
#pragma unroll
  for (int m = 0; m < 4; ++m) {
#pragma unroll
    for (int n = 0; n < 4; ++n) {
      int  gcol = bn * 256 + wn * 64 + n * 16 + l15;
      float bb  = sBias[wn * 64 + n * 16 + l15];
#pragma unroll
      for (int r = 0; r < 4; ++r) {
        long grow = (long)bm * 128 + wm * 64 + m * 16 + kq * 4 + r;
        float v = gelu_f(acc[m][n][r] + bb);
        int Mt = (int)(grow >> 7), rowpo = (int)(grow & 127);
        int Kt = gcol >> 5, kqo = (gcol >> 3) & 3, e = gcol & 7;
        long off = packed_off((long)Mt * nktOut + Kt, rowpo, kqo, e);
        unsigned short hb = f2bf(v);
        Ch[off] = hb;
        Cl[off] = f2bf(v - bf2f(hb));
      }
    }
  }
}

// ---------------------------------------------------------------------------
// PIPELINED PLAIN GEMM (dec2): 128x256 tile, BK=64 (2 k-subtiles), 8 waves,
// 2 phases/K-step, double-buffered, counted staging. OUT: f32 row-major.
// ---------------------------------------------------------------------------
__global__ __launch_bounds__(512, 1) void gemm_pipe_plain_kernel(
    const unsigned short* __restrict__ Ah, const unsigned short* __restrict__ Bh,
    int nkt /* 32k-subtiles, even */, const float* __restrict__ bias,
    float* __restrict__ Cf, long ldc, int nbn)
{
  __shared__ alignas(16) unsigned short sA[2][8192];    // [dbuf][2 ksub x 4096]
  __shared__ alignas(16) unsigned short sB[2][16384];   // [dbuf][half*2+ksub x 4096]
  __shared__ float sBias[256];

  int tid = threadIdx.x;
  int nwg = gridDim.x, q = nwg >> 3, b0 = blockIdx.x;
  int sw = (b0 & 7) * q + (b0 >> 3);
  int bm = sw / nbn, bn = sw % nbn;

  if (tid < 256) sBias[tid] = bias[bn * 256 + tid];

  int wid = tid >> 6, lane = tid & 63;
  int wm = wid >> 2, wn = wid & 3;
  int l15 = lane & 15, kq = lane >> 4;

  int aidx[4], bidx[4];
#pragma unroll
  for (int m = 0; m < 4; ++m) aidx[m] = swz_idx(wm * 64 + m * 16 + l15, kq);
#pragma unroll
  for (int n = 0; n < 4; ++n) {
    int r = wn * 64 + n * 16 + l15;
    bidx[n] = (r >> 7) * 8192 + swz_idx(r & 127, kq);
  }

  f32x4 acc[4][4] = {};
  int nks = nkt >> 1;   // K-steps of 64

  // prologue: stage K-step 0 (subtiles 0,1) into buffer 0
  {
#pragma unroll
    for (int s = 0; s < 2; ++s) {
      long at = (long)(bm * nkt + s);
      llds16((const char*)Ah + at * 8192 + tid * 16, (char*)sA[0] + s * 8192 + tid * 16);
#pragma unroll
      for (int h = 0; h < 2; ++h) {
        long bt = (long)((bn * 2 + h) * nkt + s);
        llds16((const char*)Bh + bt * 8192 + tid * 16,
               (char*)sB[0] + (h * 2 + s) * 8192 + tid * 16);
      }
    }
  }
  asm volatile("s_waitcnt vmcnt(0)");
  __builtin_amdgcn_sched_barrier(0);
  __builtin_amdgcn_s_barrier();

  for (int t = 0; t < nks; ++t) {
    int cur = t & 1, nxt = cur ^ 1;
    bool pre = (t + 1 < nks);
    short8 ah[4][2], bf[4][2];

    // ---- phase 0: A frags (both k-slices) + B[0..1]; stage A + B-half0
#pragma unroll
    for (int m = 0; m < 4; ++m)
#pragma unroll
      for (int s = 0; s < 2; ++s)
        ah[m][s] = *(const short8*)&sA[cur][s * 4096 + aidx[m]];
#pragma unroll
    for (int n = 0; n < 2; ++n)
#pragma unroll
      for (int s = 0; s < 2; ++s)
        bf[n][s] = *(const short8*)&sB[cur][n >= 2 ? 0 : bidx[n] + s * 4096];
    if (pre) {
#pragma unroll
      for (int s = 0; s < 2; ++s) {
        long at = (long)(bm * nkt + 2 * (t + 1) + s);
        llds16((const char*)Ah + at * 8192 + tid * 16, (char*)sA[nxt] + s * 8192 + tid * 16);
      }
      {
        long bt0 = (long)((bn * 2) * nkt + 2 * (t + 1));
        llds16((const char*)Bh + bt0 * 8192 + tid * 16, (char*)sB[nxt] + tid * 16);
        llds16((const char*)Bh + (bt0 + 1) * 8192 + tid * 16, (char*)sB[nxt] + 4096 * 2 + tid * 16);
      }
    }
    __builtin_amdgcn_s_barrier();
    asm volatile("s_waitcnt lgkmcnt(0)");
    __builtin_amdgcn_sched_barrier(0);
    __builtin_amdgcn_s_setprio(1);
#pragma unroll
    for (int n = 0; n < 2; ++n)
#pragma unroll
      for (int m = 0; m < 4; ++m)
#pragma unroll
        for (int s = 0; s < 2; ++s)
          acc[m][n] = mfma_bf16(ah[m][s], bf[n][s], acc[m][n]);
    __builtin_amdgcn_s_setprio(0);
    __builtin_amdgcn_sched_barrier(0);
    __builtin_amdgcn_s_barrier();

    // ---- phase 1: B[2..3]; stage B-half1
#pragma unroll
    for (int n = 2; n < 4; ++n)
#pragma unroll
      for (int s = 0; s < 2; ++s)
        bf[n][s] = *(const short8*)&sB[cur][bidx[n] + s * 4096];
    if (pre) {
      long bt1 = (long)((bn * 2 + 1) * nkt + 2 * (t + 1));
      llds16((const char*)Bh + bt1 * 8192 + tid * 16, (char*)sB[nxt] + 2 * 8192 + tid * 16);
      llds16((const char*)Bh + (bt1 + 1) * 8192 + tid * 16, (char*)sB[nxt] + 3 * 8192 + tid * 16);
    }
    __builtin_amdgcn_s_barrier();
    asm volatile("s_waitcnt lgkmcnt(0)");
    __builtin_amdgcn_sched_barrier(0);
    __builtin_amdgcn_s_setprio(1);
#pragma unroll
    for (int n = 2; n < 4; ++n)
#pragma unroll
      for (int m = 0; m < 4; ++m)
#pragma unroll
        for (int s = 0; s < 2; ++s)
          acc[m][n] = mfma_bf16(ah[m][s], bf[n][s], acc[m][n]);
    __builtin_amdgcn_s_setprio(0);
    __builtin_amdgcn_sched_barrier(0);
    __builtin_amdgcn_s_barrier();

    // ---- end of K-step
    asm volatile("s_waitcnt vmcnt(0)");
    __builtin_amdgcn_sched_barrier(0);
    __builtin_amdgcn_s_barrier();
  }

#pragma unroll
  for (int m = 0; m < 4; ++m) {
#pragma unroll
    for (int n = 0; n < 4; ++n) {
      int  gcol = bn * 256 + wn * 64 + n * 16 + l15;
      float bb  = sBias[wn * 64 + n * 16 + l15];
#pragma unroll
      for (int r = 0; r < 4; ++r) {
        long grow = (long)bm * 128 + wm * 64 + m * 16 + kq * 4 + r;
        Cf[grow * ldc + gcol] = acc[m][n][r] + bb;
      }
    }
  }
}

// ---------------------------------------------------------------------------
// 128^2 GEMM (kept for enc2): packed-swizzled operands, split-bf16.
// ---------------------------------------------------------------------------
template<bool SPLIT, int OUT_MODE, bool GELU>
__global__ __launch_bounds__(256) void gemm2_kernel(
    const unsigned short* __restrict__ Ah, const unsigned short* __restrict__ Al,
    const unsigned short* __restrict__ Bh, const unsigned short* __restrict__ Bl,
    int nkt, const float* __restrict__ bias, float* __restrict__ Cf,
    unsigned short* __restrict__ Ch, unsigned short* __restrict__ Cl,
    long ldc, int nktOut, int nbn)
{
  __shared__ alignas(16) unsigned short sAh[4096];
  __shared__ alignas(16) unsigned short sAl[SPLIT ? 4096 : 8];
  __shared__ alignas(16) unsigned short sBh[4096];
  __shared__ alignas(16) unsigned short sBl[SPLIT ? 4096 : 8];
  __shared__ float sBias[128];

  int tid = threadIdx.x;
  int nwg = gridDim.x, q = nwg >> 3, b0 = blockIdx.x;
  int sw = (b0 & 7) * q + (b0 >> 3);
  int bm = sw / nbn, bn = sw % nbn;

  if (tid < 128) sBias[tid] = bias[bn * 128 + tid];

  int wid = tid >> 6, lane = tid & 63;
  int wm = wid >> 1, wn = wid & 1;
  int l15 = lane & 15, kq = lane >> 4;

  f32x4 acc[4][4] = {};

  for (int kt = 0; kt < nkt; ++kt) {
    __syncthreads();
    {
      const char* gA = (const char*)Ah + ((long)(bm * nkt + kt)) * 8192 + tid * 16;
      llds16(gA,        (char*)sAh + tid * 16);
      llds16(gA + 4096, (char*)sAh + 4096 + tid * 16);
    }
    if constexpr (SPLIT) {
      const char* gA = (const char*)Al + ((long)(bm * nkt + kt)) * 8192 + tid * 16;
      llds16(gA,        (char*)sAl + tid * 16);
      llds16(gA + 4096, (char*)sAl + 4096 + tid * 16);
    }
    {
      const char* gB = (const char*)Bh + ((long)(bn * nkt + kt)) * 8192 + tid * 16;
      llds16(gB,        (char*)sBh + tid * 16);
      llds16(gB + 4096, (char*)sBh + 4096 + tid * 16);
    }
    if constexpr (SPLIT) {
      const char* gB = (const char*)Bl + ((long)(bn * nkt + kt)) * 8192 + tid * 16;
      llds16(gB,        (char*)sBl + tid * 16);
      llds16(gB + 4096, (char*)sBl + 4096 + tid * 16);
    }
    __syncthreads();

    short8 bh[4], bl[4];
#pragma unroll
    for (int n = 0; n < 4; ++n) {
      int idx = swz_idx(wn * 64 + n * 16 + l15, kq);
      bh[n] = *(const short8*)&sBh[idx];
      if constexpr (SPLIT) bl[n] = *(const short8*)&sBl[idx];
    }
#pragma unroll
    for (int m = 0; m < 4; ++m) {
      int idx = swz_idx(wm * 64 + m * 16 + l15, kq);
      short8 ah = *(const short8*)&sAh[idx];
      short8 al;
      if constexpr (SPLIT) al = *(const short8*)&sAl[idx];
#pragma unroll
      for (int n = 0; n < 4; ++n) {
        acc[m][n] = mfma_bf16(ah, bh[n], acc[m][n]);
        if constexpr (SPLIT) {
          acc[m][n] = mfma_bf16(al, bh[n], acc[m][n]);
          acc[m][n] = mfma_bf16(ah, bl[n], acc[m][n]);
        }
      }
    }
  }

#pragma unroll
  for (int m = 0; m < 4; ++m) {
#pragma unroll
    for (int n = 0; n < 4; ++n) {
      int  gcol = bn * 128 + wn * 64 + n * 16 + l15;
      float bb  = sBias[wn * 64 + n * 16 + l15];
#pragma unroll
      for (int r = 0; r < 4; ++r) {
        long grow = (long)bm * 128 + wm * 64 + m * 16 + kq * 4 + r;
        float v = acc[m][n][r] + bb;
        if constexpr (GELU) v = gelu_f(v);
        if constexpr (OUT_MODE == 0) {
          Cf[grow * ldc + gcol] = v;
        } else {
          int Mt = (int)(grow >> 7), rowpo = (int)(grow & 127);
          int Kt = gcol >> 5, kqo = (gcol >> 3) & 3, e = gcol & 7;
          long off = packed_off((long)Mt * nktOut + Kt, rowpo, kqo, e);
          unsigned short hb = f2bf(v);
          Ch[off] = hb;
          Cl[off] = f2bf(v - bf2f(hb));
        }
      }
    }
  }
}

// ---------------------------------------------------------------------------
// Per-row top-4 (+5th for margin), softmax, mix components -> pts.
// ---------------------------------------------------------------------------
__global__ __launch_bounds__(256) void topk_kernel(
    const float* __restrict__ logits, const float* __restrict__ comp,
    float* __restrict__ pts, int* __restrict__ rescueCnt, int* __restrict__ rescueList)
{
  int wid = threadIdx.x >> 6, lane = threadIdx.x & 63;
  long row = (long)blockIdx.x * 4 + wid;
  f32x4 v4 = *(const f32x4*)(logits + row * NC + lane * 4);
  float a[4] = {v4[0], v4[1], v4[2], v4[3]};

  float tv[5]; int ti[5];
#pragma unroll
  for (int t = 0; t < 5; ++t) {
    float lv = a[0]; int li = lane * 4;
#pragma unroll
    for (int i = 1; i < 4; ++i)
      if (a[i] > lv) { lv = a[i]; li = lane * 4 + i; }
#pragma unroll
    for (int off = 32; off >= 1; off >>= 1) {
      float ov = __shfl_xor(lv, off);
      int   oi = __shfl_xor(li, off);
      if (ov > lv || (ov == lv && oi < li)) { lv = ov; li = oi; }
    }
    tv[t] = lv; ti[t] = li;
    if (t < 4 && (li >> 2) == lane) a[li & 3] = -INFINITY;
  }

  float m = tv[0], w[4], s = 0.f;
#pragma unroll
  for (int t = 0; t < 4; ++t) { w[t] = expf(tv[t] - m); s += w[t]; }
  float inv = 1.0f / s;
  if (lane < 3) {
    float p = 0.f;
#pragma unroll
    for (int t = 0; t < 4; ++t) p += w[t] * inv * comp[ti[t] * 3 + lane];
    pts[row * 3 + lane] = p;
  }
  if (lane == 0 && (tv[3] - tv[4]) < TAU) {
    int pos = atomicAdd(rescueCnt, 1);
    rescueList[pos] = (int)row;
  }
}

// ---------------------------------------------------------------------------
// PARALLEL fp64 rescue (3 stages) + serial fallback for n > MAXR.
// ---------------------------------------------------------------------------
__global__ __launch_bounds__(256) void rescue_h1_kernel(
    const float* __restrict__ x, const float* __restrict__ embedMat,
    const int* __restrict__ liPtr, const float* __restrict__ W1,
    const int* __restrict__ cnt, const int* __restrict__ list,
    double* __restrict__ partial)
{
  int b = blockIdx.x;
  int s = b / 24, rem = b % 24;
  int cc = rem >> 2, kp = rem & 3;
  int n = *cnt;
  if (s >= n || s >= MAXR) return;
  int row = list[s];
  __shared__ double xd[512];
  int tid = threadIdx.x;
  int li = liPtr[0];
  int k0 = kp * 512;
  for (int j = tid; j < 512; j += 256)
    xd[j] = (double)x[(long)row * IN_DIM + k0 + j]
          + (double)embedMat[(long)li * IN_DIM + k0 + j];
  __syncthreads();
  int c = cc * 256 + tid;
  const float* wp = W1 + (long)k0 * HID + c;
  double s0 = 0, s1 = 0, s2 = 0, s3 = 0;
  for (int k = 0; k < 512; k += 4) {
    s0 += xd[k]     * (double)wp[(long)k * HID];
    s1 += xd[k + 1] * (double)wp[(long)(k + 1) * HID];
    s2 += xd[k + 2] * (double)wp[(long)(k + 2) * HID];
    s3 += xd[k + 3] * (double)wp[(long)(k + 3) * HID];
  }
  partial[((long)(s * 6 + cc) * 4 + kp) * 256 + tid] = (s0 + s1) + (s2 + s3);
}

__global__ __launch_bounds__(256) void rescue_h2_kernel(
    const float* __restrict__ b1, const int* __restrict__ cnt,
    const double* __restrict__ partial, double* __restrict__ hbuf)
{
  int b = blockIdx.x;
  int s = b / 6, cc = b % 6;
  int n = *cnt;
  if (s >= n || s >= MAXR) return;
  int tid = threadIdx.x;
  long base = ((long)(s * 6 + cc) * 4) * 256 + tid;
  double v = (double)b1[cc * 256 + tid]
           + ((partial[base] + partial[base + 256])
            + (partial[base + 512] + partial[base + 768]));
  hbuf[(long)s * HID + cc * 256 + tid]
      = 0.5 * v * (1.0 + erf(v * 0.70710678118654752440));
}

__global__ __launch_bounds__(256) void rescue_logits_kernel(
    const float* __restrict__ W2, const float* __restrict__ b2,
    const float* __restrict__ comp, const int* __restrict__ cnt,
    const int* __restrict__ list, const double* __restrict__ hbuf,
    float* __restrict__ pts)
{
  int s = blockIdx.x;
  int n = *cnt;
  if (s >= n || s >= MAXR) return;
  __shared__ double hd[HID];
  __shared__ double ld[NC];
  int tid = threadIdx.x;
  for (int j = tid; j < HID; j += 256) hd[j] = hbuf[(long)s * HID + j];
  __syncthreads();
  {
    const float* wp = W2 + tid;
    double a0 = 0, a1 = 0, a2 = 0, a3 = 0;
    for (int k = 0; k < HID; k += 4) {
      a0 += hd[k]     * (double)wp[(long)k * NC];
      a1 += hd[k + 1] * (double)wp[(long)(k + 1) * NC];
      a2 += hd[k + 2] * (double)wp[(long)(k + 2) * NC];
      a3 += hd[k + 3] * (double)wp[(long)(k + 3) * NC];
    }
    ld[tid] = (double)b2[tid] + ((a0 + a1) + (a2 + a3));
  }
  __syncthreads();
  if (tid == 0) {
    int row = list[s];
    int idx[4]; double val[4];
    unsigned long long mask[4] = {0, 0, 0, 0};
    for (int t = 0; t < 4; ++t) {
      double bv = -1e300; int bi = 0;
      for (int j = 0; j < NC; ++j) {
        if ((mask[j >> 6] >> (j & 63)) & 1ull) continue;
        if (ld[j] > bv) { bv = ld[j]; bi = j; }
      }
      idx[t] = bi; val[t] = bv; mask[bi >> 6] |= 1ull << (bi & 63);
    }
    double m = val[0], w[4], sum = 0;
    for (int t = 0; t < 4; ++t) { w[t] = exp(val[t] - m); sum += w[t]; }
    for (int c = 0; c < 3; ++c) {
      double p = 0;
      for (int t = 0; t < 4; ++t) p += (w[t] / sum) * (double)comp[idx[t] * 3 + c];
      pts[(long)row * 3 + c] = (float)p;
    }
  }
}

__global__ __launch_bounds__(256) void rescue_slow_kernel(
    const float* __restrict__ x, const float* __restrict__ embedMat,
    const int* __restrict__ liPtr, const float* __restrict__ W1,
    const float* __restrict__ b1, const float* __restrict__ W2,
    const float* __restrict__ b2, const float* __restrict__ comp,
    float* __restrict__ pts, const int* __restrict__ cnt, const int* __restrict__ list)
{
  __shared__ double xd[IN_DIM];
  __shared__ double hd[HID];
  __shared__ double ld[NC];
  int tid = threadIdx.x;
  int li = liPtr[0];
  int n = *cnt;
  for (int it = MAXR + blockIdx.x; it < n; it += gridDim.x) {
    int row = list[it];
    const float* xr = x + (long)row * IN_DIM;
    const float* er = embedMat + (long)li * IN_DIM;
    for (int j = tid; j < IN_DIM; j += 256)
      xd[j] = (double)xr[j] + (double)er[j];
    __syncthreads();
    for (int c = tid; c < HID; c += 256) {
      double s0 = 0, s1 = 0, s2 = 0, s3 = 0;
      const float* wp = W1 + c;
      for (int k = 0; k < IN_DIM; k += 4) {
        s0 += xd[k]     * (double)wp[(long)k * HID];
        s1 += xd[k + 1] * (double)wp[(long)(k + 1) * HID];
        s2 += xd[k + 2] * (double)wp[(long)(k + 2) * HID];
        s3 += xd[k + 3] * (double)wp[(long)(k + 3) * HID];
      }
      double s = (double)b1[c] + ((s0 + s1) + (s2 + s3));
      hd[c] = 0.5 * s * (1.0 + erf(s * 0.70710678118654752440));
    }
    __syncthreads();
    {
      int c = tid;
      double s0 = 0, s1 = 0, s2 = 0, s3 = 0;
      const float* wp = W2 + c;
      for (int k = 0; k < HID; k += 4) {
        s0 += hd[k]     * (double)wp[(long)k * NC];
        s1 += hd[k + 1] * (double)wp[(long)(k + 1) * NC];
        s2 += hd[k + 2] * (double)wp[(long)(k + 2) * NC];
        s3 += hd[k + 3] * (double)wp[(long)(k + 3) * NC];
      }
      ld[c] = (double)b2[c] + ((s0 + s1) + (s2 + s3));
    }
    __syncthreads();
    if (tid == 0) {
      int idx[4]; double val[4];
      unsigned long long mask[4] = {0, 0, 0, 0};
      for (int t = 0; t < 4; ++t) {
        double bv = -1e300; int bi = 0;
        for (int j = 0; j < NC; ++j) {
          if ((mask[j >> 6] >> (j & 63)) & 1ull) continue;
          if (ld[j] > bv) { bv = ld[j]; bi = j; }
        }
        idx[t] = bi; val[t] = bv; mask[bi >> 6] |= 1ull << (bi & 63);
      }
      double m = val[0], w[4], s = 0;
      for (int t = 0; t < 4; ++t) { w[t] = exp(val[t] - m); s += w[t]; }
      for (int c = 0; c < 3; ++c) {
        double p = 0;
        for (int t = 0; t < 4; ++t) p += (w[t] / s) * (double)comp[idx[t] * 3 + c];
        pts[(long)row * 3 + c] = (float)p;
      }
    }
    __syncthreads();
  }
}

// ---------------------------------------------------------------------------
// d = gelu(pts @ dec_w1 + dec_b1), stored packed-swizzled bf16 (dec2's A).
// ---------------------------------------------------------------------------
__global__ __launch_bounds__(256) void dec_a_kernel(
    const float* __restrict__ pts, const float* __restrict__ W1d,
    const float* __restrict__ b1d, unsigned short* __restrict__ dout)
{
  int  j = (blockIdx.x % 6) * 256 + threadIdx.x;
  long b = blockIdx.x / 6;
  const float* p = pts + b * 3;
  float s = fmaf(p[0], W1d[j], fmaf(p[1], W1d[HID + j], fmaf(p[2], W1d[2 * HID + j], b1d[j])));
  int Mt = (int)(b >> 7), rowp = (int)(b & 127);
  int Kt = j >> 5, kq = (j >> 3) & 3, e = j & 7;
  dout[packed_off((long)Mt * NKT2 + Kt, rowp, kq, e)] = f2bf(gelu_f(s));
}

__global__ __launch_bounds__(256) void enc_out_kernel(
    const float* __restrict__ comp, float* __restrict__ out)
{
  long base = (long)blockIdx.x * 768;
  int  t = threadIdx.x;
  out[base + t]       = comp[t];
  out[base + 256 + t] = comp[256 + t];
  out[base + 512 + t] = comp[512 + t];
}

__global__ void zero_cnt_kernel(int* c) { if (threadIdx.x == 0) *c = 0; }

// ---------------------------------------------------------------------------
extern "C" void kernel_launch(void* const* d_in, const int* in_sizes, int n_in,
                              void* d_out, int out_size, void* d_ws, size_t ws_size,
                              hipStream_t stream) {
  const float* x     = (const float*)d_in[0];
  const int*   liPtr = (const int*)  d_in[1];
  const float* embed = (const float*)d_in[2];
  const float* W1    = (const float*)d_in[3];
  const float* b1    = (const float*)d_in[4];
  const float* W2    = (const float*)d_in[5];
  const float* b2    = (const float*)d_in[6];
  const float* comp  = (const float*)d_in[7];
  const float* W1d   = (const float*)d_in[8];
  const float* b1d   = (const float*)d_in[9];
  const float* W2d   = (const float*)d_in[10];
  const float* b2d   = (const float*)d_in[11];
  float* out = (float*)d_out;

  char* w = (char*)d_ws;
  unsigned short* W1hT = (unsigned short*)(w);
  unsigned short* W1lT = (unsigned short*)(w + 6291456);
  unsigned short* W2hT = (unsigned short*)(w + 12582912);
  unsigned short* W2lT = (unsigned short*)(w + 13369344);
  unsigned short* W2dT = (unsigned short*)(w + 14155776);
  constexpr size_t A0 = 20447232;

  unsigned short* Xh = (unsigned short*)(w + A0);
  unsigned short* Xl = (unsigned short*)(w + A0 + 67108864);
  unsigned short* Hh = (unsigned short*)(w + A0 + 134217728);
  unsigned short* Hl = (unsigned short*)(w + A0 + 184549376);
  float*  logits  = (float*)(w + A0);
  float*  pts     = (float*)(w + A0 + 16777216);
  int*    cnt     = (int*)  (w + A0 + 16973824);
  int*    list    = (int*)  (w + A0 + 16974080);
  double* partial = (double*)(w + A0 + 17108992);
  double* hbuf    = (double*)(w + A0 + 20254720);
  unsigned short* dbuf = Xl;

  transpose_split_kernel<<<dim3(HID / 32, IN_DIM / 32), 256, 0, stream>>>(W1, IN_DIM, HID, NKT1, W1hT, W1lT);
  transpose_split_kernel<<<dim3(NC / 32, HID / 32),     256, 0, stream>>>(W2, HID, NC, NKT2, W2hT, W2lT);
  transpose_split_kernel<<<dim3(IN_DIM / 32, HID / 32), 256, 0, stream>>>(W2d, HID, IN_DIM, NKT2, W2dT, nullptr);

  split_x_kernel<<<NB * IN_DIM / 2048, 256, 0, stream>>>(x, embed, liPtr, Xh, Xl);

  // enc1: (Hh,Hl) = split(gelu((x+embed) @ W1 + b1))  [pipelined split GEMM]
  gemm_pipe_split_kernel<<<(NB / 128) * (HID / 256), 512, 0, stream>>>(
      Xh, Xl, W1hT, W1lT, NKT1, b1, Hh, Hl, NKT2, HID / 256);
  // enc2: logits = h @ W2 + b2                         [128^2 split GEMM]
  gemm2_kernel<true, 0, false><<<(NB / 128) * (NC / 128), 256, 0, stream>>>(
      Hh, Hl, W2hT, W2lT, NKT2, b2, logits, nullptr, nullptr, NC, 0, NC / 128);

  zero_cnt_kernel<<<1, 64, 0, stream>>>(cnt);
  topk_kernel<<<NB / 4, 256, 0, stream>>>(logits, comp, pts, cnt, list);
  rescue_h1_kernel<<<MAXR * 24, 256, 0, stream>>>(x, embed, liPtr, W1, cnt, list, partial);
  rescue_h2_kernel<<<MAXR * 6,  256, 0, stream>>>(b1, cnt, partial, hbuf);
  rescue_logits_kernel<<<MAXR,  256, 0, stream>>>(W2, b2, comp, cnt, list, hbuf, pts);
  rescue_slow_kernel<<<64, 256, 0, stream>>>(x, embed, liPtr, W1, b1, W2, b2, comp, pts, cnt, list);

  dec_a_kernel<<<NB * (HID / 256), 256, 0, stream>>>(pts, W1d, b1d, dbuf);
  // dec2: decoded = d @ W2d + b2d                      [pipelined plain GEMM]
  gemm_pipe_plain_kernel<<<(NB / 128) * (IN_DIM / 256), 512, 0, stream>>>(
      dbuf, W2dT, NKT2, b2d, out + ENC_ELEMS, IN_DIM, IN_DIM / 256);

  enc_out_kernel<<<NB, 256, 0, stream>>>(comp, out);
}